// Round 20
// baseline (84.722 us; speedup 1.0000x reference)
//
#include <hip/hip_runtime.h>
#include <math.h>

#define DD 4096
#define EE 64
#define NTOK 8192
#define BM 128           // tokens per block
#define KC 32            // K-chunk per pipeline step
#define NMB (NTOK / BM)  // 64 m-blocks
#define KS 8             // K-split
#define WSTR 40          // W LDS row stride in bf16 (80 B, 16B-aligned)
#define TAU 4e-3f        // near-tie flag threshold (split err ~1e-5 RMS)

typedef __attribute__((ext_vector_type(8))) short short8;
typedef __attribute__((ext_vector_type(4))) float f32x4;

__device__ __forceinline__ unsigned short f2bf(float f) {   // RNE bf16
    unsigned int u = __float_as_uint(f);
    return (unsigned short)((u + 0x7FFFu + ((u >> 16) & 1u)) >> 16);
}
__device__ __forceinline__ float bf2f(unsigned short h) {
    return __uint_as_float((unsigned int)h << 16);
}

// ---------------------------------------------------------------------------
// prep: W -> bf16 hi/lo split (Wh, Wl). Pre-converting (not in-loop) matters:
// at 2 blocks/CU the in-loop cvt VALU work is unhidden (r19: +23us).
// ---------------------------------------------------------------------------
__global__ void moirai_prep(const float* __restrict__ W,
                            unsigned short* __restrict__ Wh,
                            unsigned short* __restrict__ Wl) {
    int i = blockIdx.x * 256 + threadIdx.x;
    if (i < EE * DD) {
        float w = W[i];
        unsigned short h = f2bf(w);
        Wh[i] = h;
        Wl[i] = f2bf(w - bf2f(h));
    }
}

// ---------------------------------------------------------------------------
// gemm (r13 champion, byte-identical core): 3-term split-bf16 MFMA.
// Block = 256 thr (4 waves) = 128 tok x 64 exp x K-slice. Wave wv: m-frags
// {2wv,2wv+1}, n-frags 0..3 -> 24 MFMA per K=32 step.
// x: global_load_lds dwordx4 x16/step, src-swizzled k^4*(r&7) ->
//    conflict-free ds_read_b128 fragments; cvt f32->bf16 hi/lo at read.
// W: prep'd bf16 global->reg->ds_write per step (stride-40 rows).
// ONE __syncthreads per step drains everything. Partials -> part[ks][tok][e].
// ---------------------------------------------------------------------------
__global__ __launch_bounds__(256, 2) void moirai_gemm(
        const float* __restrict__ x,
        const unsigned short* __restrict__ Wh,
        const unsigned short* __restrict__ Wl,
        float* __restrict__ part) {
    __shared__ __align__(16) float          xs[2][BM * KC];     // 32 KB
    __shared__ __align__(16) unsigned short whs[2][EE * WSTR];  // 10 KB
    __shared__ __align__(16) unsigned short wls[2][EE * WSTR];  // 10 KB

    const int t    = threadIdx.x;
    const int lane = t & 63;
    const int wv   = t >> 6;             // wave 0..3
    const int mblk = blockIdx.x & (NMB - 1);
    const int ks   = blockIdx.x >> 6;    // grid = NMB * KS
    const int m0   = mblk * BM;
    const int k0   = ks * (DD / KS);

    const int fr = lane & 15;            // fragment row (token / expert)
    const int fg = lane >> 4;            // k-group (8 elems)

    const int we  = t >> 2;              // W staging: row 0..63
    const int wsg = t & 3;               // 8-bf16 segment 0..3

    f32x4 accH[2][4], accL[2][4];
#pragma unroll
    for (int mf = 0; mf < 2; mf++)
#pragma unroll
        for (int nt = 0; nt < 4; nt++) {
            accH[mf][nt] = f32x4{0.f, 0.f, 0.f, 0.f};
            accL[mf][nt] = f32x4{0.f, 0.f, 0.f, 0.f};
        }

    // x staging: wave wv issues 4 global_load_lds (1 KB each, LDS-linear).
    auto stage_x = [&](int p, int c) {
        const int kb = k0 + c * KC;
#pragma unroll
        for (int j = 0; j < 4; j++) {
            const int r = wv * 32 + j * 8 + (lane >> 3);
            const int k = ((lane & 7) * 4) ^ (4 * (r & 7));
            const float* gp = x + (size_t)(m0 + r) * DD + kb + k;
            float* lp = &xs[p][(wv * 4 + j) * 256];   // wave-uniform base
            __builtin_amdgcn_global_load_lds(
                (const __attribute__((address_space(1))) void*)gp,
                (__attribute__((address_space(3))) void*)lp, 16, 0, 0);
        }
    };

    uint4 whr, wlr;
    auto ldW = [&](int c) {
        const int kb = k0 + c * KC;
        whr = *(const uint4*)(Wh + (size_t)we * DD + kb + wsg * 8);
        wlr = *(const uint4*)(Wl + (size_t)we * DD + kb + wsg * 8);
    };
    auto stW = [&](int p) {
        *(uint4*)&whs[p][we * WSTR + wsg * 8] = whr;
        *(uint4*)&wls[p][we * WSTR + wsg * 8] = wlr;
    };

    auto compute = [&](int p) {
        short8 ah[2], al[2], bh[4], bl[4];
#pragma unroll
        for (int mf = 0; mf < 2; mf++) {
            const int r = (wv * 2 + mf) * 16 + fr;
            const int q = 4 * (fr & 7);          // r&7 == fr&7
            const float4 a0 = *(const float4*)&xs[p][r * 32 + ((fg * 8) ^ q)];
            const float4 a1 = *(const float4*)&xs[p][r * 32 + ((fg * 8 + 4) ^ q)];
            const float v[8] = {a0.x, a0.y, a0.z, a0.w, a1.x, a1.y, a1.z, a1.w};
#pragma unroll
            for (int i = 0; i < 8; i++) {
                unsigned short hh = f2bf(v[i]);
                ah[mf][i] = (short)hh;
                al[mf][i] = (short)f2bf(v[i] - bf2f(hh));
            }
        }
#pragma unroll
        for (int nt = 0; nt < 4; nt++) {
            const int e = nt * 16 + fr;
            bh[nt] = *(const short8*)&whs[p][e * WSTR + fg * 8];
            bl[nt] = *(const short8*)&wls[p][e * WSTR + fg * 8];
        }
#pragma unroll
        for (int mf = 0; mf < 2; mf++)
#pragma unroll
            for (int nt = 0; nt < 4; nt++) {
                accH[mf][nt] = __builtin_amdgcn_mfma_f32_16x16x32_bf16(
                    ah[mf], bh[nt], accH[mf][nt], 0, 0, 0);
                accL[mf][nt] = __builtin_amdgcn_mfma_f32_16x16x32_bf16(
                    ah[mf], bl[nt], accL[mf][nt], 0, 0, 0);
                accL[mf][nt] = __builtin_amdgcn_mfma_f32_16x16x32_bf16(
                    al[mf], bh[nt], accL[mf][nt], 0, 0, 0);
            }
    };

    const int nch = (DD / KS) / KC;      // 16
    ldW(0);
    stage_x(0, 0);
    stW(0);
    __syncthreads();                     // buf 0 staged & visible

    for (int c = 0; c < nch; c++) {
        const int p = c & 1;
        if (c + 1 < nch) {
            stage_x(p ^ 1, c + 1);       // async DMA into other buffer
            ldW(c + 1);                  // W regs in flight under compute
        }
        compute(p);
        if (c + 1 < nch) stW(p ^ 1);     // vmcnt wait auto-inserted here
        __syncthreads();                 // drain + visibility, once per step
    }

    // C/D (verified m89/m91): col = lane&15 -> expert, row = fg*4+j -> token
#pragma unroll
    for (int mf = 0; mf < 2; mf++)
#pragma unroll
        for (int nt = 0; nt < 4; nt++)
#pragma unroll
            for (int j = 0; j < 4; j++) {
                const int token = m0 + (wv * 2 + mf) * 16 + fg * 4 + j;
                const float v = accH[mf][nt][j] + accL[mf][nt][j];
                part[((size_t)ks * NTOK + token) * EE + nt * 16 + fr] = v;
            }
}

// ---------------------------------------------------------------------------
// topk: wave per token, lane = expert. f32 sum of KS partials (fixed order,
// deterministic) + bias -> ballot top-3 (lowest-index tie-break = jax).
// flag[token] written unconditionally (0/1) -> no reset, poison-immune.
// Output: [gate_probs 16384 f32][indices-as-f32 16384].
// ---------------------------------------------------------------------------
__global__ void moirai_topk(const float* __restrict__ part,
                            const float* __restrict__ bias,
                            float* __restrict__ out,
                            unsigned char* __restrict__ flag) {
    const int lane  = threadIdx.x & 63;
    const int token = blockIdx.x * 4 + (threadIdx.x >> 6);

    float v = bias[lane];
#pragma unroll
    for (int ks = 0; ks < KS; ks++)
        v += part[((size_t)ks * NTOK + token) * EE + lane];

    float m1 = v;
#pragma unroll
    for (int off = 1; off < 64; off <<= 1) m1 = fmaxf(m1, __shfl_xor(m1, off));
    const unsigned long long b1 = __ballot(v == m1);
    const int i1 = (int)__ffsll(b1) - 1;              // lowest index (jax)

    const float vm2 = (lane == i1) ? -3.4e38f : v;
    float m2 = vm2;
#pragma unroll
    for (int off = 1; off < 64; off <<= 1) m2 = fmaxf(m2, __shfl_xor(m2, off));
    const unsigned long long b2 = __ballot(vm2 == m2 && lane != i1);
    const int i2 = (int)__ffsll(b2) - 1;

    const float vm3 = (lane == i1 || lane == i2) ? -3.4e38f : v;
    float m3 = vm3;
#pragma unroll
    for (int off = 1; off < 64; off <<= 1) m3 = fmaxf(m3, __shfl_xor(m3, off));

    if (lane == 0) {
        flag[token] = ((m1 - m2 < TAU) || (m2 - m3 < TAU)) ? 1 : 0;
        double ex = exp((double)m2 - (double)m1);     // m1 >= m2 -> stable
        double s  = 1.0 + ex;
        out[token * 2 + 0] = (float)(1.0 / s);
        out[token * 2 + 1] = (float)(ex / s);
        out[NTOK * 2 + token * 2 + 0] = (float)i1;
        out[NTOK * 2 + token * 2 + 1] = (float)i2;
    }
}

// ---------------------------------------------------------------------------
// fix: exact f64 recompute of flagged rows. Grid 256, block 1024; block b
// owns tokens b + i*256; flags preloaded to LDS (block-uniform branch).
// x row staged in LDS; 16 lanes/expert -> coalesced 64B W reads;
// shfl-tree reduce -> wave 0 f64 top-2 (validated comparator).
// ---------------------------------------------------------------------------
__global__ __launch_bounds__(1024) void moirai_fix(
        const float* __restrict__ x, const float* __restrict__ W,
        const float* __restrict__ bias,
        const unsigned char* __restrict__ flag,
        float* __restrict__ out) {
    __shared__ float  xsr[DD];      // 16 KB
    __shared__ double red[EE];
    __shared__ unsigned char flg[32];

    const int t = threadIdx.x;
    const int e = t >> 4;           // expert 0..63
    const int j = t & 15;           // k-strip within expert

    if (t < 32) flg[t] = flag[blockIdx.x + t * 256];
    __syncthreads();

    for (int i = 0; i < 32; i++) {
        if (!flg[i]) continue;                 // block-uniform
        const int token = blockIdx.x + i * 256;

        *(float4*)&xsr[t * 4] = *(const float4*)(x + (size_t)token * DD + t * 4);
        __syncthreads();

        const float* wr = W + (size_t)e * DD;
        double a0 = 0.0, a1 = 0.0, a2 = 0.0, a3 = 0.0;
#pragma unroll 8
        for (int ii = 0; ii < DD / 64; ii++) {
            const int k = ii * 64 + j * 4;
            const float4 xv = *(const float4*)&xsr[k];
            const float4 wv = *(const float4*)(wr + k);
            a0 += (double)xv.x * (double)wv.x;
            a1 += (double)xv.y * (double)wv.y;
            a2 += (double)xv.z * (double)wv.z;
            a3 += (double)xv.w * (double)wv.w;
        }
        double s = (a0 + a1) + (a2 + a3);
#pragma unroll
        for (int off = 1; off < 16; off <<= 1)
            s += __shfl_xor(s, off);           // within 16-lane group
        if (j == 0) red[e] = s;
        __syncthreads();

        if (t < 64) {                          // wave 0: f64 top-2
            double vd = red[t] + (double)bias[t];
            double e1 = vd, e2 = -1.0e300;
            int    f1 = t,  f2 = 127;
#pragma unroll
            for (int off = 1; off < 64; off <<= 1) {
                double u1 = __shfl_xor(e1, off);
                double u2 = __shfl_xor(e2, off);
                int    j1 = __shfl_xor(f1, off);
                int    j2 = __shfl_xor(f2, off);
                bool u1_beats_e1 = (u1 > e1) || (u1 == e1 && j1 < f1);
                if (u1_beats_e1) {
                    bool e1_beats_u2 = (e1 > u2) || (e1 == u2 && f1 < j2);
                    if (e1_beats_u2) { e2 = e1; f2 = f1; }
                    else             { e2 = u2; f2 = j2; }
                    e1 = u1; f1 = j1;
                } else {
                    bool u1_beats_e2 = (u1 > e2) || (u1 == e2 && j1 < f2);
                    if (u1_beats_e2) { e2 = u1; f2 = j1; }
                }
            }
            if (t == 0) {
                double ex = exp(e2 - e1);
                double sm = 1.0 + ex;
                out[token * 2 + 0] = (float)(1.0 / sm);
                out[token * 2 + 1] = (float)(ex / sm);
                out[NTOK * 2 + token * 2 + 0] = (float)f1;
                out[NTOK * 2 + token * 2 + 1] = (float)f2;
            }
        }
        __syncthreads();   // LDS reuse guard
    }
}

// ---------------------------------------------------------------------------
extern "C" void kernel_launch(void* const* d_in, const int* in_sizes, int n_in,
                              void* d_out, int out_size, void* d_ws, size_t ws_size,
                              hipStream_t stream) {
    const float* x = (const float*)d_in[0];
    const float* W = (const float*)d_in[1];
    const float* b = (const float*)d_in[2];
    float* out = (float*)d_out;

    // ws layout: [flag 8192 B, padded to 64 KB][Wh 512 KB][Wl 512 KB][part].
    // flag fully overwritten by topk each call -> no reset, poison-immune.
    const size_t HDR = 65536;
    const size_t WSZ = (size_t)EE * DD * 2;
    unsigned char*  flag = (unsigned char*)d_ws;
    unsigned short* Wh   = (unsigned short*)((char*)d_ws + HDR);
    unsigned short* Wl   = (unsigned short*)((char*)d_ws + HDR + WSZ);
    float*          part = (float*)((char*)d_ws + HDR + 2 * WSZ);

    moirai_prep<<<(EE * DD + 255) / 256, 256, 0, stream>>>(W, Wh, Wl);
    moirai_gemm<<<NMB * KS, 256, 0, stream>>>(x, Wh, Wl, part);
    moirai_topk<<<NTOK / 4, 256, 0, stream>>>(part, b, out, flag);
    moirai_fix<<<256, 1024, 0, stream>>>(x, W, b, flag, out);
}

// Round 21
// 50.716 us; speedup vs baseline: 1.6705x; 1.6705x over previous
//
#include <hip/hip_runtime.h>
#include <math.h>

#define DD 4096
#define EE 64
#define NTOK 8192
#define BM 128           // tokens per block
#define KC 32            // K-chunk per pipeline step
#define NMB (NTOK / BM)  // 64 m-blocks
#define KS 8             // K-split
#define WSTR 40          // W LDS row stride in bf16 (80 B, 16B-aligned)
#define TAU 4e-3f        // near-tie flag threshold (split err ~1e-5 RMS)
#define DTA 1e-3f        // candidate slack: 2x worst-case f32-path error

typedef __attribute__((ext_vector_type(8))) short short8;
typedef __attribute__((ext_vector_type(4))) float f32x4;

__device__ __forceinline__ unsigned short f2bf(float f) {   // RNE bf16
    unsigned int u = __float_as_uint(f);
    return (unsigned short)((u + 0x7FFFu + ((u >> 16) & 1u)) >> 16);
}
__device__ __forceinline__ float bf2f(unsigned short h) {
    return __uint_as_float((unsigned int)h << 16);
}

// ---------------------------------------------------------------------------
// prep: W -> bf16 hi/lo split (Wh, Wl).
// ---------------------------------------------------------------------------
__global__ void moirai_prep(const float* __restrict__ W,
                            unsigned short* __restrict__ Wh,
                            unsigned short* __restrict__ Wl) {
    int i = blockIdx.x * 256 + threadIdx.x;
    if (i < EE * DD) {
        float w = W[i];
        unsigned short h = f2bf(w);
        Wh[i] = h;
        Wl[i] = f2bf(w - bf2f(h));
    }
}

// ---------------------------------------------------------------------------
// gemm (r13 champion core): 3-term split-bf16 MFMA. Block = 256 thr (4
// waves) = 128 tok x 64 exp x K-slice. Wave wv: m-frags {2wv,2wv+1},
// n-frags 0..3 -> 24 MFMA per K=32 step.
// x: global_load_lds dwordx4 x16/step, src-swizzled k^4*(r&7) ->
//    conflict-free ds_read_b128 fragments; cvt f32->bf16 hi/lo at read.
// W: prep'd bf16 global->reg->ds_write per step (stride-40 rows).
// Block 0 zeroes the flag counter (kernel boundary orders it before topk).
// ---------------------------------------------------------------------------
__global__ __launch_bounds__(256, 2) void moirai_gemm(
        const float* __restrict__ x,
        const unsigned short* __restrict__ Wh,
        const unsigned short* __restrict__ Wl,
        float* __restrict__ part, int* __restrict__ count) {
    __shared__ __align__(16) float          xs[2][BM * KC];     // 32 KB
    __shared__ __align__(16) unsigned short whs[2][EE * WSTR];  // 10 KB
    __shared__ __align__(16) unsigned short wls[2][EE * WSTR];  // 10 KB

    const int t    = threadIdx.x;
    const int lane = t & 63;
    const int wv   = t >> 6;             // wave 0..3
    const int mblk = blockIdx.x & (NMB - 1);
    const int ks   = blockIdx.x >> 6;    // grid = NMB * KS
    const int m0   = mblk * BM;
    const int k0   = ks * (DD / KS);

    if (blockIdx.x == 0 && t == 0) *count = 0;

    const int fr = lane & 15;            // fragment row (token / expert)
    const int fg = lane >> 4;            // k-group (8 elems)

    const int we  = t >> 2;              // W staging: row 0..63
    const int wsg = t & 3;               // 8-bf16 segment 0..3

    f32x4 accH[2][4], accL[2][4];
#pragma unroll
    for (int mf = 0; mf < 2; mf++)
#pragma unroll
        for (int nt = 0; nt < 4; nt++) {
            accH[mf][nt] = f32x4{0.f, 0.f, 0.f, 0.f};
            accL[mf][nt] = f32x4{0.f, 0.f, 0.f, 0.f};
        }

    auto stage_x = [&](int p, int c) {
        const int kb = k0 + c * KC;
#pragma unroll
        for (int j = 0; j < 4; j++) {
            const int r = wv * 32 + j * 8 + (lane >> 3);
            const int k = ((lane & 7) * 4) ^ (4 * (r & 7));
            const float* gp = x + (size_t)(m0 + r) * DD + kb + k;
            float* lp = &xs[p][(wv * 4 + j) * 256];   // wave-uniform base
            __builtin_amdgcn_global_load_lds(
                (const __attribute__((address_space(1))) void*)gp,
                (__attribute__((address_space(3))) void*)lp, 16, 0, 0);
        }
    };

    uint4 whr, wlr;
    auto ldW = [&](int c) {
        const int kb = k0 + c * KC;
        whr = *(const uint4*)(Wh + (size_t)we * DD + kb + wsg * 8);
        wlr = *(const uint4*)(Wl + (size_t)we * DD + kb + wsg * 8);
    };
    auto stW = [&](int p) {
        *(uint4*)&whs[p][we * WSTR + wsg * 8] = whr;
        *(uint4*)&wls[p][we * WSTR + wsg * 8] = wlr;
    };

    auto compute = [&](int p) {
        short8 ah[2], al[2], bh[4], bl[4];
#pragma unroll
        for (int mf = 0; mf < 2; mf++) {
            const int r = (wv * 2 + mf) * 16 + fr;
            const int q = 4 * (fr & 7);          // r&7 == fr&7
            const float4 a0 = *(const float4*)&xs[p][r * 32 + ((fg * 8) ^ q)];
            const float4 a1 = *(const float4*)&xs[p][r * 32 + ((fg * 8 + 4) ^ q)];
            const float v[8] = {a0.x, a0.y, a0.z, a0.w, a1.x, a1.y, a1.z, a1.w};
#pragma unroll
            for (int i = 0; i < 8; i++) {
                unsigned short hh = f2bf(v[i]);
                ah[mf][i] = (short)hh;
                al[mf][i] = (short)f2bf(v[i] - bf2f(hh));
            }
        }
#pragma unroll
        for (int nt = 0; nt < 4; nt++) {
            const int e = nt * 16 + fr;
            bh[nt] = *(const short8*)&whs[p][e * WSTR + fg * 8];
            bl[nt] = *(const short8*)&wls[p][e * WSTR + fg * 8];
        }
#pragma unroll
        for (int mf = 0; mf < 2; mf++)
#pragma unroll
            for (int nt = 0; nt < 4; nt++) {
                accH[mf][nt] = __builtin_amdgcn_mfma_f32_16x16x32_bf16(
                    ah[mf], bh[nt], accH[mf][nt], 0, 0, 0);
                accL[mf][nt] = __builtin_amdgcn_mfma_f32_16x16x32_bf16(
                    ah[mf], bl[nt], accL[mf][nt], 0, 0, 0);
                accL[mf][nt] = __builtin_amdgcn_mfma_f32_16x16x32_bf16(
                    al[mf], bh[nt], accL[mf][nt], 0, 0, 0);
            }
    };

    const int nch = (DD / KS) / KC;      // 16
    ldW(0);
    stage_x(0, 0);
    stW(0);
    __syncthreads();                     // buf 0 staged & visible

    for (int c = 0; c < nch; c++) {
        const int p = c & 1;
        if (c + 1 < nch) {
            stage_x(p ^ 1, c + 1);       // async DMA into other buffer
            ldW(c + 1);                  // W regs in flight under compute
        }
        compute(p);
        if (c + 1 < nch) stW(p ^ 1);     // vmcnt wait auto-inserted here
        __syncthreads();                 // drain + visibility, once per step
    }

    // C/D (verified m89/m91): col = lane&15 -> expert, row = fg*4+j -> token
#pragma unroll
    for (int mf = 0; mf < 2; mf++)
#pragma unroll
        for (int nt = 0; nt < 4; nt++)
#pragma unroll
            for (int j = 0; j < 4; j++) {
                const int token = m0 + (wv * 2 + mf) * 16 + fg * 4 + j;
                const float v = accH[mf][nt][j] + accL[mf][nt][j];
                part[((size_t)ks * NTOK + token) * EE + nt * 16 + fr] = v;
            }
}

// ---------------------------------------------------------------------------
// topk: wave per token, lane = expert. f32 sum of KS partials (fixed order)
// + bias -> ballot top-3 (lowest-index tie-break = jax). Near-tie rows
// appended to list (count zeroed by gemm block 0 each launch).
// ---------------------------------------------------------------------------
__global__ void moirai_topk(const float* __restrict__ part,
                            const float* __restrict__ bias,
                            float* __restrict__ out,
                            int* __restrict__ count, int* __restrict__ list) {
    const int lane  = threadIdx.x & 63;
    const int token = blockIdx.x * 4 + (threadIdx.x >> 6);

    float v = bias[lane];
#pragma unroll
    for (int ks = 0; ks < KS; ks++)
        v += part[((size_t)ks * NTOK + token) * EE + lane];

    float m1 = v;
#pragma unroll
    for (int off = 1; off < 64; off <<= 1) m1 = fmaxf(m1, __shfl_xor(m1, off));
    const unsigned long long b1 = __ballot(v == m1);
    const int i1 = (int)__ffsll(b1) - 1;              // lowest index (jax)

    const float vm2 = (lane == i1) ? -3.4e38f : v;
    float m2 = vm2;
#pragma unroll
    for (int off = 1; off < 64; off <<= 1) m2 = fmaxf(m2, __shfl_xor(m2, off));
    const unsigned long long b2 = __ballot(vm2 == m2 && lane != i1);
    const int i2 = (int)__ffsll(b2) - 1;

    const float vm3 = (lane == i1 || lane == i2) ? -3.4e38f : v;
    float m3 = vm3;
#pragma unroll
    for (int off = 1; off < 64; off <<= 1) m3 = fmaxf(m3, __shfl_xor(m3, off));

    if (lane == 0) {
        if ((m1 - m2 < TAU) || (m2 - m3 < TAU)) {
            int pos = atomicAdd(count, 1);
            list[pos] = token;
        }
        double ex = exp((double)m2 - (double)m1);     // m1 >= m2 -> stable
        double s  = 1.0 + ex;
        out[token * 2 + 0] = (float)(1.0 / s);
        out[token * 2 + 1] = (float)(ex / s);
        out[NTOK * 2 + token * 2 + 0] = (float)i1;
        out[NTOK * 2 + token * 2 + 1] = (float)i2;
    }
}

// ---------------------------------------------------------------------------
// fix: candidate-filtered exact recompute. One 256-thr block per flagged row
// (grid-stride over list -> balanced, 1 row/block at ~80 rows).
// f32 logits (same order as topk) bound truth within delta; only experts
// with v_f32 >= m2_f32 - DTA (superset of exact top-2, typically 2-3) get
// f64 dots: 256-thread coalesced dot + fixed-order tree reduce (~1us/row,
// vs ~12us for the old full-row f64 path — r17 measured).
// ---------------------------------------------------------------------------
__global__ __launch_bounds__(256) void moirai_fix(
        const float* __restrict__ x, const float* __restrict__ W,
        const float* __restrict__ bias,
        const float* __restrict__ part,
        const int* __restrict__ count, const int* __restrict__ list,
        float* __restrict__ out) {
    __shared__ __align__(16) float xsr[DD];   // 16 KB
    __shared__ float  vf[EE];
    __shared__ float  m2s;
    __shared__ unsigned long long candmask;
    __shared__ double dred[256];
    __shared__ double eval[EE];

    const int t = threadIdx.x;
    const int n = *count;

    for (int idx = blockIdx.x; idx < n; idx += gridDim.x) {
        const int token = list[idx];

        // stage x row (coalesced float4)
#pragma unroll
        for (int i = 0; i < 4; i++)
            *(float4*)&xsr[i * 1024 + t * 4] =
                *(const float4*)(x + (size_t)token * DD + i * 1024 + t * 4);

        // wave 0: f32 logits (same summation order as topk) + m2
        if (t < 64) {
            float v = bias[t];
#pragma unroll
            for (int ks = 0; ks < KS; ks++)
                v += part[((size_t)ks * NTOK + token) * EE + t];
            vf[t] = v;
            float m1 = v;
#pragma unroll
            for (int off = 1; off < 64; off <<= 1)
                m1 = fmaxf(m1, __shfl_xor(m1, off));
            const unsigned long long b1 = __ballot(v == m1);
            const int i1 = (int)__ffsll(b1) - 1;
            float vm2 = (t == i1) ? -3.4e38f : v;
            float m2 = vm2;
#pragma unroll
            for (int off = 1; off < 64; off <<= 1)
                m2 = fmaxf(m2, __shfl_xor(m2, off));
            unsigned long long cm = __ballot(v >= m2 - DTA);
            if (t == 0) { m2s = m2; candmask = cm; }
        }
        __syncthreads();

        // exact f64 dot for each candidate expert (block-uniform loop)
        unsigned long long cm = candmask;
        while (cm) {
            const int e = (int)__ffsll(cm) - 1;
            cm &= cm - 1;
            double a = 0.0;
#pragma unroll
            for (int i = 0; i < 4; i++) {
                const float4 xv = *(const float4*)&xsr[i * 1024 + t * 4];
                const float4 wv = *(const float4*)(W + (size_t)e * DD + i * 1024 + t * 4);
                a += (double)xv.x * (double)wv.x;
                a += (double)xv.y * (double)wv.y;
                a += (double)xv.z * (double)wv.z;
                a += (double)xv.w * (double)wv.w;
            }
            dred[t] = a;
            __syncthreads();
            if (t < 64) {
                double s = (dred[t] + dred[t + 64]) + (dred[t + 128] + dred[t + 192]);
#pragma unroll
                for (int off = 1; off < 64; off <<= 1)
                    s += __shfl_xor(s, off);      // fixed order: deterministic
                if (t == 0) eval[e] = s + (double)bias[e];
            }
            __syncthreads();
        }

        if (t == 0) {
            unsigned long long m = candmask;
            double b1v = -1.0e300, b2v = -1.0e300;
            int    b1i = 127,      b2i = 127;
            while (m) {       // ascending e; strict > keeps lower index (jax)
                const int e = (int)__ffsll(m) - 1;
                m &= m - 1;
                const double v = eval[e];
                if (v > b1v)      { b2v = b1v; b2i = b1i; b1v = v; b1i = e; }
                else if (v > b2v) { b2v = v; b2i = e; }
            }
            double ex = exp(b2v - b1v);
            double sm = 1.0 + ex;
            out[token * 2 + 0] = (float)(1.0 / sm);
            out[token * 2 + 1] = (float)(ex / sm);
            out[NTOK * 2 + token * 2 + 0] = (float)b1i;
            out[NTOK * 2 + token * 2 + 1] = (float)b2i;
        }
        __syncthreads();   // LDS reuse guard for next grid-stride row
    }
}

// ---------------------------------------------------------------------------
extern "C" void kernel_launch(void* const* d_in, const int* in_sizes, int n_in,
                              void* d_out, int out_size, void* d_ws, size_t ws_size,
                              hipStream_t stream) {
    const float* x = (const float*)d_in[0];
    const float* W = (const float*)d_in[1];
    const float* b = (const float*)d_in[2];
    float* out = (float*)d_out;

    // ws layout: [count 4B | list 8192*4B, padded to 64 KB][Wh][Wl][part].
    // count zeroed by gemm block 0 every launch (kernel-boundary ordered
    // before topk's atomics) -> poison-immune.
    const size_t HDR = 65536;
    const size_t WSZ = (size_t)EE * DD * 2;
    int*            count = (int*)d_ws;
    int*            list  = (int*)d_ws + 1;
    unsigned short* Wh    = (unsigned short*)((char*)d_ws + HDR);
    unsigned short* Wl    = (unsigned short*)((char*)d_ws + HDR + WSZ);
    float*          part  = (float*)((char*)d_ws + HDR + 2 * WSZ);

    moirai_prep<<<(EE * DD + 255) / 256, 256, 0, stream>>>(W, Wh, Wl);
    moirai_gemm<<<NMB * KS, 256, 0, stream>>>(x, Wh, Wl, part, count);
    moirai_topk<<<NTOK / 4, 256, 0, stream>>>(part, b, out, count, list);
    moirai_fix<<<256, 256, 0, stream>>>(x, W, b, part, count, list, out);
}